// Round 1
// baseline (1884.934 us; speedup 1.0000x reference)
//
#include <hip/hip_runtime.h>

#define F1 64
#define F2 32
#define FIN 13

// ---------- init: deg=1 (self loop), zero pool sums/counts ----------
__global__ void k_init(float* __restrict__ deg, float* __restrict__ sums,
                       float* __restrict__ counts, int N, int G) {
    int i = blockIdx.x * blockDim.x + threadIdx.x;
    if (i < N) deg[i] = 1.0f;
    if (i < G * F2) sums[i] = 0.0f;
    if (i < G) counts[i] = 0.0f;
}

// ---------- in-degree via atomics ----------
__global__ void k_degree(const int* __restrict__ dst, float* __restrict__ deg, int E) {
    int e = blockIdx.x * blockDim.x + threadIdx.x;
    if (e < E) atomicAdd(&deg[dst[e]], 1.0f);
}

// ---------- deg -> rsqrt(deg) in place ----------
__global__ void k_rsqrt(float* __restrict__ deg, int N) {
    int i = blockIdx.x * blockDim.x + threadIdx.x;
    if (i < N) deg[i] = rsqrtf(deg[i]);
}

// ---------- layer1 transform: y1 = (x@W1)*dinv ; out1 = (x@W1)*dinv^2 + b1 ----------
// 256 threads = 4 nodes x 64 cols
__global__ void k_xw1(const float* __restrict__ x, const float* __restrict__ W1,
                      const float* __restrict__ b1, const float* __restrict__ dinv,
                      float* __restrict__ y1, float* __restrict__ out1, int N) {
    __shared__ float sW[FIN * F1];
    __shared__ float sb[F1];
    int tid = threadIdx.x;
    for (int i = tid; i < FIN * F1; i += blockDim.x) sW[i] = W1[i];
    if (tid < F1) sb[tid] = b1[tid];
    __syncthreads();
    int node = blockIdx.x * 4 + (tid >> 6);
    int c = tid & 63;
    if (node >= N) return;
    const float* xr = x + (size_t)node * FIN;
    float acc = 0.f;
#pragma unroll
    for (int k = 0; k < FIN; ++k) acc += xr[k] * sW[k * F1 + c];
    float dv = dinv[node];
    float yv = acc * dv;
    y1[(size_t)node * F1 + c] = yv;
    out1[(size_t)node * F1 + c] = yv * dv + sb[c];
}

// ---------- edge scatter: out[dst] += y[src]*dinv[dst], F/4 threads per edge ----------
template <int F>
__global__ void k_scatter(const int* __restrict__ src, const int* __restrict__ dst,
                          const float* __restrict__ dinv, const float4* __restrict__ y,
                          float* __restrict__ out, int E) {
    const int TPE = F / 4;
    int tid = blockIdx.x * blockDim.x + threadIdx.x;
    int e = tid / TPE;
    int t = tid % TPE;
    if (e >= E) return;
    int s = src[e];
    int d = dst[e];
    float nrm = dinv[d];
    float4 v = y[(size_t)s * TPE + t];
    float* o = out + (size_t)d * F + t * 4;
    atomicAdd(o + 0, v.x * nrm);
    atomicAdd(o + 1, v.y * nrm);
    atomicAdd(o + 2, v.z * nrm);
    atomicAdd(o + 3, v.w * nrm);
}

// ---------- layer2 transform: h=relu(out1); y2=(h@W2)*dinv ; out2=(h@W2)*dinv^2+b2 ----------
// 256 threads = 8 nodes x 32 cols
__global__ void k_layer2(const float* __restrict__ out1, const float* __restrict__ W2,
                         const float* __restrict__ b2, const float* __restrict__ dinv,
                         float* __restrict__ y2, float* __restrict__ out2, int N) {
    __shared__ float sW[F1 * F2];
    __shared__ float sb[F2];
    __shared__ float sh[8][F1];
    int tid = threadIdx.x;
    for (int i = tid; i < F1 * F2; i += blockDim.x) sW[i] = W2[i];
    if (tid < F2) sb[tid] = b2[tid];
    int ng = tid >> 5;       // node group 0..7
    int c = tid & 31;        // col
    int node = blockIdx.x * 8 + ng;
    if (node < N) {
        sh[ng][c] = fmaxf(out1[(size_t)node * F1 + c], 0.f);
        sh[ng][c + 32] = fmaxf(out1[(size_t)node * F1 + c + 32], 0.f);
    }
    __syncthreads();
    if (node >= N) return;
    float acc = 0.f;
#pragma unroll
    for (int k = 0; k < F1; ++k) acc += sh[ng][k] * sW[k * F2 + c];
    float dv = dinv[node];
    float yv = acc * dv;
    y2[(size_t)node * F2 + c] = yv;
    out2[(size_t)node * F2 + c] = yv * dv + sb[c];
}

// ---------- mean-pool accumulation ----------
__global__ void k_pool(const float* __restrict__ out2, const int* __restrict__ batch,
                       float* __restrict__ sums, float* __restrict__ counts, int N) {
    int tid = blockIdx.x * blockDim.x + threadIdx.x;
    int v = tid >> 5;
    int c = tid & 31;
    if (v >= N) return;
    int g = batch[v];
    atomicAdd(&sums[(size_t)g * F2 + c], out2[(size_t)v * F2 + c]);
    if (c == 0) atomicAdd(&counts[g], 1.0f);
}

// ---------- final MLP: g=sums/cnt; relu(g@fc1+b); @fc2+b -> out ----------
// 256 threads = 8 graphs x 32 cols
__global__ void k_mlp(const float* __restrict__ sums, const float* __restrict__ counts,
                      const float* __restrict__ fc1w, const float* __restrict__ fc1b,
                      const float* __restrict__ fc2w, const float* __restrict__ fc2b,
                      float* __restrict__ out, int G) {
    __shared__ float sW1[F2 * F2];
    __shared__ float sW2[F2 * F2];
    __shared__ float sb1[F2], sb2[F2];
    __shared__ float sg[8][F2];
    __shared__ float sh1[8][F2];
    int tid = threadIdx.x;
    for (int i = tid; i < F2 * F2; i += blockDim.x) {
        sW1[i] = fc1w[i];
        sW2[i] = fc2w[i];
    }
    if (tid < F2) { sb1[tid] = fc1b[tid]; sb2[tid] = fc2b[tid]; }
    int gg = tid >> 5;
    int c = tid & 31;
    int g = blockIdx.x * 8 + gg;
    if (g < G) {
        float cnt = fmaxf(counts[g], 1.0f);
        sg[gg][c] = sums[(size_t)g * F2 + c] / cnt;
    }
    __syncthreads();
    float acc = 0.f;
#pragma unroll
    for (int k = 0; k < F2; ++k) acc += sg[gg][k] * sW1[k * F2 + c];
    sh1[gg][c] = fmaxf(acc + sb1[c], 0.f);
    __syncthreads();
    float acc2 = 0.f;
#pragma unroll
    for (int k = 0; k < F2; ++k) acc2 += sh1[gg][k] * sW2[k * F2 + c];
    if (g < G) out[(size_t)g * F2 + c] = acc2 + sb2[c];
}

extern "C" void kernel_launch(void* const* d_in, const int* in_sizes, int n_in,
                              void* d_out, int out_size, void* d_ws, size_t ws_size,
                              hipStream_t stream) {
    const float* x    = (const float*)d_in[0];
    const int*   ei   = (const int*)d_in[1];
    const int*   batch= (const int*)d_in[2];
    const float* W1   = (const float*)d_in[3];
    const float* b1   = (const float*)d_in[4];
    const float* W2   = (const float*)d_in[5];
    const float* b2   = (const float*)d_in[6];
    const float* fc1w = (const float*)d_in[7];
    const float* fc1b = (const float*)d_in[8];
    const float* fc2w = (const float*)d_in[9];
    const float* fc2b = (const float*)d_in[10];
    float* out = (float*)d_out;

    const int N = in_sizes[0] / FIN;       // 100000
    const int E = in_sizes[1] / 2;         // 1250000
    const int G = out_size / F2;           // 512
    const int* src = ei;
    const int* dst = ei + E;

    // workspace layout (floats)
    float* ws = (float*)d_ws;
    size_t nAlign = (size_t)((N + 63) & ~63);
    float* dinv   = ws;                          // N (deg -> dinv in place)
    float* y1     = dinv + nAlign;               // N*64 ; reused: y2 (N*32) + out2 (N*32)
    float* out1   = y1 + (size_t)N * F1;         // N*64
    float* sums   = out1 + (size_t)N * F1;       // G*32
    float* counts = sums + (size_t)G * F2;       // G
    float* y2   = y1;
    float* out2 = y1 + (size_t)N * F2;

    const int B = 256;
    int initN = (N > G * F2) ? N : G * F2;
    hipLaunchKernelGGL(k_init, dim3((initN + B - 1) / B), dim3(B), 0, stream,
                       dinv, sums, counts, N, G);
    hipLaunchKernelGGL(k_degree, dim3((E + B - 1) / B), dim3(B), 0, stream, dst, dinv, E);
    hipLaunchKernelGGL(k_rsqrt, dim3((N + B - 1) / B), dim3(B), 0, stream, dinv, N);

    hipLaunchKernelGGL(k_xw1, dim3((N + 3) / 4), dim3(B), 0, stream,
                       x, W1, b1, dinv, y1, out1, N);
    {
        long th = (long)E * (F1 / 4);
        hipLaunchKernelGGL((k_scatter<F1>), dim3((th + B - 1) / B), dim3(B), 0, stream,
                           src, dst, dinv, (const float4*)y1, out1, E);
    }
    hipLaunchKernelGGL(k_layer2, dim3((N + 7) / 8), dim3(B), 0, stream,
                       out1, W2, b2, dinv, y2, out2, N);
    {
        long th = (long)E * (F2 / 4);
        hipLaunchKernelGGL((k_scatter<F2>), dim3((th + B - 1) / B), dim3(B), 0, stream,
                           src, dst, dinv, (const float4*)y2, out2, E);
    }
    hipLaunchKernelGGL(k_pool, dim3(((long)N * F2 + B - 1) / B), dim3(B), 0, stream,
                       out2, batch, sums, counts, N);
    hipLaunchKernelGGL(k_mlp, dim3((G + 7) / 8), dim3(B), 0, stream,
                       sums, counts, fc1w, fc1b, fc2w, fc2b, out, G);
}

// Round 2
// 426.217 us; speedup vs baseline: 4.4225x; 4.4225x over previous
//
#include <hip/hip_runtime.h>

#define F1 64
#define F2 32
#define FIN 13
#define SCAN_B 256

// ---------- in-degree histogram (int atomics, L2-resident) ----------
__global__ void k_degree(const int* __restrict__ dst, int* __restrict__ indeg, int E) {
    int e = blockIdx.x * blockDim.x + threadIdx.x;
    if (e < E) atomicAdd(&indeg[dst[e]], 1);
}

// ---------- scan stage 1: per-block sums ----------
__global__ void k_scan1(const int* __restrict__ indeg, int* __restrict__ bsum, int N) {
    __shared__ int s[SCAN_B];
    int t = threadIdx.x;
    int i = blockIdx.x * SCAN_B + t;
    s[t] = (i < N) ? indeg[i] : 0;
    __syncthreads();
    for (int off = SCAN_B / 2; off > 0; off >>= 1) {
        if (t < off) s[t] += s[t + off];
        __syncthreads();
    }
    if (t == 0) bsum[blockIdx.x] = s[0];
}

// ---------- scan stage 2: exclusive scan of block sums (1 block, 512 thr) ----------
__global__ void k_scan2(int* __restrict__ bsum, int NB) {
    __shared__ int s[512];
    int t = threadIdx.x;
    int v = (t < NB) ? bsum[t] : 0;
    s[t] = v;
    __syncthreads();
    for (int off = 1; off < 512; off <<= 1) {
        int a = (t >= off) ? s[t - off] : 0;
        __syncthreads();
        s[t] += a;
        __syncthreads();
    }
    if (t < NB) bsum[t] = s[t] - v;   // exclusive
}

// ---------- scan stage 3: rowstart/cursor = global exclusive; dinv = rsqrt(deg+1) ----------
__global__ void k_scan3(const int* __restrict__ indeg, const int* __restrict__ bsum,
                        int* __restrict__ rowstart, int* __restrict__ cursor,
                        float* __restrict__ dinv, int N) {
    __shared__ int s[SCAN_B];
    int t = threadIdx.x;
    int i = blockIdx.x * SCAN_B + t;
    int v = (i < N) ? indeg[i] : 0;
    s[t] = v;
    __syncthreads();
    for (int off = 1; off < SCAN_B; off <<= 1) {
        int a = (t >= off) ? s[t - off] : 0;
        __syncthreads();
        s[t] += a;
        __syncthreads();
    }
    if (i < N) {
        int excl = bsum[blockIdx.x] + s[t] - v;
        rowstart[i] = excl;
        cursor[i] = excl;
        dinv[i] = rsqrtf((float)(v + 1));
    }
}

// ---------- CSR fill: csr[cursor[dst]++] = src ----------
__global__ void k_fill_csr(const int* __restrict__ src, const int* __restrict__ dst,
                           int* __restrict__ cursor, int* __restrict__ csr, int E) {
    int e = blockIdx.x * blockDim.x + threadIdx.x;
    if (e < E) {
        int d = dst[e];
        int pos = atomicAdd(&cursor[d], 1);
        csr[pos] = src[e];
    }
}

// ---------- xn[v][0..15] = x[v][c]*dinv[v] (c<13), 0 pad ----------
__global__ void k_xn(const float* __restrict__ x, const float* __restrict__ dinv,
                     float* __restrict__ xn, int N) {
    int i = blockIdx.x * blockDim.x + threadIdx.x;
    if (i >= N * 16) return;
    int v = i >> 4, c = i & 15;
    xn[i] = (c < FIN) ? x[(size_t)v * FIN + c] * dinv[v] : 0.f;
}

// ---------- layer1: aggregate xn (16 cols) then transform @W1 +b1, relu -> h ----------
// phase A: 64 nodes x 4 lanes (float4); phase B: 16 iters of 4 nodes x 64 cols
__global__ void k_agg1t(const float4* __restrict__ xn, const int* __restrict__ rowstart,
                        const int* __restrict__ indeg, const float* __restrict__ dinv,
                        const int* __restrict__ csr, const float* __restrict__ W1,
                        const float* __restrict__ b1, float* __restrict__ h, int N) {
    __shared__ float sW[FIN * F1];
    __shared__ float sb[F1];
    __shared__ float sagg[64][16];
    int tid = threadIdx.x;
    for (int i = tid; i < FIN * F1; i += 256) sW[i] = W1[i];
    if (tid < F1) sb[tid] = b1[tid];
    int ln = tid >> 2;      // local node 0..63
    int l = tid & 3;        // float4 lane
    int v = blockIdx.x * 64 + ln;
    if (v < N) {
        int st = rowstart[v];
        int dg = indeg[v];
        float4 acc = xn[(size_t)v * 4 + l];   // self term (xn already has one dinv)
        for (int e = 0; e < dg; ++e) {
            int s = csr[st + e];
            float4 u = xn[(size_t)s * 4 + l];
            acc.x += u.x; acc.y += u.y; acc.z += u.z; acc.w += u.w;
        }
        float dv = dinv[v];
        sagg[ln][l * 4 + 0] = acc.x * dv;
        sagg[ln][l * 4 + 1] = acc.y * dv;
        sagg[ln][l * 4 + 2] = acc.z * dv;
        sagg[ln][l * 4 + 3] = acc.w * dv;
    }
    __syncthreads();
    int col = tid & 63;
    int sub = tid >> 6;     // 0..3
    int base = blockIdx.x * 64;
    for (int nn = sub; nn < 64; nn += 4) {
        int v2 = base + nn;
        if (v2 >= N) break;
        float acc = sb[col];
#pragma unroll
        for (int k = 0; k < FIN; ++k) acc += sagg[nn][k] * sW[k * F1 + col];
        h[(size_t)v2 * F1 + col] = fmaxf(acc, 0.f);
    }
}

// ---------- layer2 transform: y2 = (h@W2)*dinv  (h already relu'd) ----------
// 256 threads = 8 nodes x 32 cols
__global__ void k_trans2(const float* __restrict__ h, const float* __restrict__ W2,
                         const float* __restrict__ dinv, float* __restrict__ y2, int N) {
    __shared__ float sW[F1 * F2];
    __shared__ float sh[8][F1];
    int tid = threadIdx.x;
    for (int i = tid; i < F1 * F2; i += 256) sW[i] = W2[i];
    int ng = tid >> 5;
    int c = tid & 31;
    int node = blockIdx.x * 8 + ng;
    if (node < N) {
        sh[ng][c] = h[(size_t)node * F1 + c];
        sh[ng][c + 32] = h[(size_t)node * F1 + c + 32];
    }
    __syncthreads();
    if (node >= N) return;
    float acc = 0.f;
#pragma unroll
    for (int k = 0; k < F1; ++k) acc += sh[ng][k] * sW[k * F2 + c];
    y2[(size_t)node * F2 + c] = acc * dinv[node];
}

// ---------- layer2 aggregate: out2 = dinv*(y2[self] + sum y2[src]) + b2 ----------
// 256 threads = 32 nodes x 8 lanes (float4)
__global__ void k_agg2(const float4* __restrict__ y2, const int* __restrict__ rowstart,
                       const int* __restrict__ indeg, const float* __restrict__ dinv,
                       const int* __restrict__ csr, const float* __restrict__ b2,
                       float4* __restrict__ out2, int N) {
    int tid = threadIdx.x;
    int ln = tid >> 3;      // 0..31
    int l = tid & 7;
    int v = blockIdx.x * 32 + ln;
    if (v >= N) return;
    int st = rowstart[v];
    int dg = indeg[v];
    float4 acc = y2[(size_t)v * 8 + l];
    for (int e = 0; e < dg; ++e) {
        int s = csr[st + e];
        float4 u = y2[(size_t)s * 8 + l];
        acc.x += u.x; acc.y += u.y; acc.z += u.z; acc.w += u.w;
    }
    float dv = dinv[v];
    float4 bb = ((const float4*)b2)[l];
    float4 o;
    o.x = acc.x * dv + bb.x;
    o.y = acc.y * dv + bb.y;
    o.z = acc.z * dv + bb.z;
    o.w = acc.w * dv + bb.w;
    out2[(size_t)v * 8 + l] = o;
}

// ---------- mean-pool accumulation (atomics; batch sorted) ----------
__global__ void k_pool(const float* __restrict__ out2, const int* __restrict__ batch,
                       float* __restrict__ sums, float* __restrict__ counts, int N) {
    int tid = blockIdx.x * blockDim.x + threadIdx.x;
    int v = tid >> 5;
    int c = tid & 31;
    if (v >= N) return;
    int g = batch[v];
    atomicAdd(&sums[(size_t)g * F2 + c], out2[(size_t)v * F2 + c]);
    if (c == 0) atomicAdd(&counts[g], 1.0f);
}

// ---------- final MLP ----------
__global__ void k_mlp(const float* __restrict__ sums, const float* __restrict__ counts,
                      const float* __restrict__ fc1w, const float* __restrict__ fc1b,
                      const float* __restrict__ fc2w, const float* __restrict__ fc2b,
                      float* __restrict__ out, int G) {
    __shared__ float sW1[F2 * F2];
    __shared__ float sW2[F2 * F2];
    __shared__ float sb1[F2], sb2[F2];
    __shared__ float sg[8][F2];
    __shared__ float sh1[8][F2];
    int tid = threadIdx.x;
    for (int i = tid; i < F2 * F2; i += 256) {
        sW1[i] = fc1w[i];
        sW2[i] = fc2w[i];
    }
    if (tid < F2) { sb1[tid] = fc1b[tid]; sb2[tid] = fc2b[tid]; }
    int gg = tid >> 5;
    int c = tid & 31;
    int g = blockIdx.x * 8 + gg;
    if (g < G) {
        float cnt = fmaxf(counts[g], 1.0f);
        sg[gg][c] = sums[(size_t)g * F2 + c] / cnt;
    }
    __syncthreads();
    float acc = 0.f;
#pragma unroll
    for (int k = 0; k < F2; ++k) acc += sg[gg][k] * sW1[k * F2 + c];
    sh1[gg][c] = fmaxf(acc + sb1[c], 0.f);
    __syncthreads();
    float acc2 = 0.f;
#pragma unroll
    for (int k = 0; k < F2; ++k) acc2 += sh1[gg][k] * sW2[k * F2 + c];
    if (g < G) out[(size_t)g * F2 + c] = acc2 + sb2[c];
}

extern "C" void kernel_launch(void* const* d_in, const int* in_sizes, int n_in,
                              void* d_out, int out_size, void* d_ws, size_t ws_size,
                              hipStream_t stream) {
    const float* x    = (const float*)d_in[0];
    const int*   ei   = (const int*)d_in[1];
    const int*   batch= (const int*)d_in[2];
    const float* W1   = (const float*)d_in[3];
    const float* b1   = (const float*)d_in[4];
    const float* W2   = (const float*)d_in[5];
    const float* b2   = (const float*)d_in[6];
    const float* fc1w = (const float*)d_in[7];
    const float* fc1b = (const float*)d_in[8];
    const float* fc2w = (const float*)d_in[9];
    const float* fc2b = (const float*)d_in[10];
    float* out = (float*)d_out;

    const int N = in_sizes[0] / FIN;       // 100000
    const int E = in_sizes[1] / 2;         // 1250000
    const int G = out_size / F2;           // 512
    const int* src = ei;
    const int* dst = ei + E;
    const int NB = (N + SCAN_B - 1) / SCAN_B;   // 391

    // ---- workspace layout (4-byte units) ----
    int* wsi = (int*)d_ws;
    int* indeg    = wsi;                 // N
    int* rowstart = indeg + N;           // N
    int* cursor   = rowstart + N;        // N
    int* bsum     = cursor + N;          // 512
    int* csr      = bsum + 512;          // E
    size_t ioff = (size_t)(3 * N + 512) + E;
    ioff = (ioff + 3) & ~(size_t)3;      // 16B align for float4
    float* dinv   = (float*)(wsi + ioff);            // N
    size_t nal = (size_t)((N + 3) & ~3);
    float* xn     = dinv + nal;                      // N*16
    float* y2     = xn + (size_t)N * 16;             // N*32
    float* h      = y2 + (size_t)N * F2;             // N*64
    float* out2   = h + (size_t)N * F1;              // N*32
    float* sums   = out2 + (size_t)N * F2;           // G*32
    float* counts = sums + (size_t)G * F2;           // G

    const int B = 256;
    hipMemsetAsync(indeg, 0, (size_t)N * sizeof(int), stream);
    hipMemsetAsync(sums, 0, (size_t)(G * F2 + G) * sizeof(float), stream);

    hipLaunchKernelGGL(k_degree, dim3((E + B - 1) / B), dim3(B), 0, stream, dst, indeg, E);
    hipLaunchKernelGGL(k_scan1, dim3(NB), dim3(SCAN_B), 0, stream, indeg, bsum, N);
    hipLaunchKernelGGL(k_scan2, dim3(1), dim3(512), 0, stream, bsum, NB);
    hipLaunchKernelGGL(k_scan3, dim3(NB), dim3(SCAN_B), 0, stream,
                       indeg, bsum, rowstart, cursor, dinv, N);
    hipLaunchKernelGGL(k_fill_csr, dim3((E + B - 1) / B), dim3(B), 0, stream,
                       src, dst, cursor, csr, E);
    hipLaunchKernelGGL(k_xn, dim3(((long)N * 16 + B - 1) / B), dim3(B), 0, stream,
                       x, dinv, xn, N);
    hipLaunchKernelGGL(k_agg1t, dim3((N + 63) / 64), dim3(B), 0, stream,
                       (const float4*)xn, rowstart, indeg, dinv, csr, W1, b1, h, N);
    hipLaunchKernelGGL(k_trans2, dim3((N + 7) / 8), dim3(B), 0, stream,
                       h, W2, dinv, y2, N);
    hipLaunchKernelGGL(k_agg2, dim3((N + 31) / 32), dim3(B), 0, stream,
                       (const float4*)y2, rowstart, indeg, dinv, csr, b2,
                       (float4*)out2, N);
    hipLaunchKernelGGL(k_pool, dim3(((long)N * F2 + B - 1) / B), dim3(B), 0, stream,
                       out2, batch, sums, counts, N);
    hipLaunchKernelGGL(k_mlp, dim3((G + 7) / 8), dim3(B), 0, stream,
                       sums, counts, fc1w, fc1b, fc2w, fc2b, out, G);
}

// Round 3
// 289.564 us; speedup vs baseline: 6.5096x; 1.4719x over previous
//
#include <hip/hip_runtime.h>

#define F1 64
#define F2 32
#define FIN 13
#define SCAN_B 256

// ---------- in-degree histogram (int atomics, L2-resident) ----------
__global__ void k_degree(const int* __restrict__ dst, int* __restrict__ indeg, int E) {
    int e = blockIdx.x * blockDim.x + threadIdx.x;
    if (e < E) atomicAdd(&indeg[dst[e]], 1);
}

// ---------- scan stage 1: per-block sums ----------
__global__ void k_scan1(const int* __restrict__ indeg, int* __restrict__ bsum, int N) {
    __shared__ int s[SCAN_B];
    int t = threadIdx.x;
    int i = blockIdx.x * SCAN_B + t;
    s[t] = (i < N) ? indeg[i] : 0;
    __syncthreads();
    for (int off = SCAN_B / 2; off > 0; off >>= 1) {
        if (t < off) s[t] += s[t + off];
        __syncthreads();
    }
    if (t == 0) bsum[blockIdx.x] = s[0];
}

// ---------- scan stage 2: exclusive scan of block sums (1 block, 512 thr) ----------
__global__ void k_scan2(int* __restrict__ bsum, int NB) {
    __shared__ int s[512];
    int t = threadIdx.x;
    int v = (t < NB) ? bsum[t] : 0;
    s[t] = v;
    __syncthreads();
    for (int off = 1; off < 512; off <<= 1) {
        int a = (t >= off) ? s[t - off] : 0;
        __syncthreads();
        s[t] += a;
        __syncthreads();
    }
    if (t < NB) bsum[t] = s[t] - v;   // exclusive
}

// ---------- scan stage 3: rowstart/cursor = global exclusive; dinv = rsqrt(deg+1) ----------
__global__ void k_scan3(const int* __restrict__ indeg, const int* __restrict__ bsum,
                        int* __restrict__ rowstart, int* __restrict__ cursor,
                        float* __restrict__ dinv, int N) {
    __shared__ int s[SCAN_B];
    int t = threadIdx.x;
    int i = blockIdx.x * SCAN_B + t;
    int v = (i < N) ? indeg[i] : 0;
    s[t] = v;
    __syncthreads();
    for (int off = 1; off < SCAN_B; off <<= 1) {
        int a = (t >= off) ? s[t - off] : 0;
        __syncthreads();
        s[t] += a;
        __syncthreads();
    }
    if (i < N) {
        int excl = bsum[blockIdx.x] + s[t] - v;
        rowstart[i] = excl;
        cursor[i] = excl;
        dinv[i] = rsqrtf((float)(v + 1));
    }
}

// ---------- CSR fill: csr[cursor[dst]++] = src ----------
__global__ void k_fill_csr(const int* __restrict__ src, const int* __restrict__ dst,
                           int* __restrict__ cursor, int* __restrict__ csr, int E) {
    int e = blockIdx.x * blockDim.x + threadIdx.x;
    if (e < E) {
        int d = dst[e];
        int pos = atomicAdd(&cursor[d], 1);
        csr[pos] = src[e];
    }
}

// ---------- xn[v][0..15] = x[v][c]*dinv[v] (c<13), 0 pad ----------
__global__ void k_xn(const float* __restrict__ x, const float* __restrict__ dinv,
                     float* __restrict__ xn, int N) {
    int i = blockIdx.x * blockDim.x + threadIdx.x;
    if (i >= N * 16) return;
    int v = i >> 4, c = i & 15;
    xn[i] = (c < FIN) ? x[(size_t)v * FIN + c] * dinv[v] : 0.f;
}

// ---------- layer1: aggregate xn (16 cols) then transform @W1 +b1, relu -> h ----------
__global__ void k_agg1t(const float4* __restrict__ xn, const int* __restrict__ rowstart,
                        const int* __restrict__ indeg, const float* __restrict__ dinv,
                        const int* __restrict__ csr, const float* __restrict__ W1,
                        const float* __restrict__ b1, float* __restrict__ h, int N) {
    __shared__ float sW[FIN * F1];
    __shared__ float sb[F1];
    __shared__ float sagg[64][16];
    int tid = threadIdx.x;
    for (int i = tid; i < FIN * F1; i += 256) sW[i] = W1[i];
    if (tid < F1) sb[tid] = b1[tid];
    int ln = tid >> 2;      // local node 0..63
    int l = tid & 3;        // float4 lane
    int v = blockIdx.x * 64 + ln;
    if (v < N) {
        int st = rowstart[v];
        int dg = indeg[v];
        float4 acc = xn[(size_t)v * 4 + l];   // self term (xn already has one dinv)
        for (int e = 0; e < dg; ++e) {
            int s = csr[st + e];
            float4 u = xn[(size_t)s * 4 + l];
            acc.x += u.x; acc.y += u.y; acc.z += u.z; acc.w += u.w;
        }
        float dv = dinv[v];
        sagg[ln][l * 4 + 0] = acc.x * dv;
        sagg[ln][l * 4 + 1] = acc.y * dv;
        sagg[ln][l * 4 + 2] = acc.z * dv;
        sagg[ln][l * 4 + 3] = acc.w * dv;
    }
    __syncthreads();
    int col = tid & 63;
    int sub = tid >> 6;     // 0..3
    int base = blockIdx.x * 64;
    for (int nn = sub; nn < 64; nn += 4) {
        int v2 = base + nn;
        if (v2 >= N) break;
        float acc = sb[col];
#pragma unroll
        for (int k = 0; k < FIN; ++k) acc += sagg[nn][k] * sW[k * F1 + col];
        h[(size_t)v2 * F1 + col] = fmaxf(acc, 0.f);
    }
}

// ---------- layer2 transform: y2 = (h@W2)*dinv  (h already relu'd) ----------
__global__ void k_trans2(const float* __restrict__ h, const float* __restrict__ W2,
                         const float* __restrict__ dinv, float* __restrict__ y2, int N) {
    __shared__ float sW[F1 * F2];
    __shared__ float sh[8][F1];
    int tid = threadIdx.x;
    for (int i = tid; i < F1 * F2; i += 256) sW[i] = W2[i];
    int ng = tid >> 5;
    int c = tid & 31;
    int node = blockIdx.x * 8 + ng;
    if (node < N) {
        sh[ng][c] = h[(size_t)node * F1 + c];
        sh[ng][c + 32] = h[(size_t)node * F1 + c + 32];
    }
    __syncthreads();
    if (node >= N) return;
    float acc = 0.f;
#pragma unroll
    for (int k = 0; k < F1; ++k) acc += sh[ng][k] * sW[k * F2 + c];
    y2[(size_t)node * F2 + c] = acc * dinv[node];
}

// ---------- layer2 aggregate: out2 = dinv*(y2[self] + sum y2[src]) + b2 ----------
__global__ void k_agg2(const float4* __restrict__ y2, const int* __restrict__ rowstart,
                       const int* __restrict__ indeg, const float* __restrict__ dinv,
                       const int* __restrict__ csr, const float* __restrict__ b2,
                       float4* __restrict__ out2, int N) {
    int tid = threadIdx.x;
    int ln = tid >> 3;      // 0..31
    int l = tid & 7;
    int v = blockIdx.x * 32 + ln;
    if (v >= N) return;
    int st = rowstart[v];
    int dg = indeg[v];
    float4 acc = y2[(size_t)v * 8 + l];
    for (int e = 0; e < dg; ++e) {
        int s = csr[st + e];
        float4 u = y2[(size_t)s * 8 + l];
        acc.x += u.x; acc.y += u.y; acc.z += u.z; acc.w += u.w;
    }
    float dv = dinv[v];
    float4 bb = ((const float4*)b2)[l];
    float4 o;
    o.x = acc.x * dv + bb.x;
    o.y = acc.y * dv + bb.y;
    o.z = acc.z * dv + bb.z;
    o.w = acc.w * dv + bb.w;
    out2[(size_t)v * 8 + l] = o;
}

// ---------- graph boundaries: gstart[g] = lower_bound(batch, g), g in [0,G] ----------
__global__ void k_gstart(const int* __restrict__ batch, int* __restrict__ gstart,
                         int N, int G) {
    int g = blockIdx.x * blockDim.x + threadIdx.x;
    if (g > G) return;
    int lo = 0, hi = N;
    while (lo < hi) {
        int mid = (lo + hi) >> 1;
        if (batch[mid] < g) lo = mid + 1; else hi = mid;
    }
    gstart[g] = lo;
}

// ---------- fused mean-pool + MLP: one block per graph, no atomics ----------
__global__ void k_poolmlp(const float* __restrict__ out2, const int* __restrict__ gstart,
                          const float* __restrict__ fc1w, const float* __restrict__ fc1b,
                          const float* __restrict__ fc2w, const float* __restrict__ fc2b,
                          float* __restrict__ out, int G) {
    __shared__ float sW1[F2 * F2];
    __shared__ float sW2[F2 * F2];
    __shared__ float part[8][F2];
    __shared__ float gvec[F2];
    __shared__ float h1[F2];
    int tid = threadIdx.x;
    for (int i = tid; i < F2 * F2; i += 256) {
        sW1[i] = fc1w[i];
        sW2[i] = fc2w[i];
    }
    int g = blockIdx.x;
    int st = gstart[g], en = gstart[g + 1];
    int r = tid >> 5, c = tid & 31;
    float acc = 0.f;
    for (int v = st + r; v < en; v += 8) acc += out2[(size_t)v * F2 + c];
    part[r][c] = acc;
    __syncthreads();
    if (tid < F2) {
        float s = 0.f;
#pragma unroll
        for (int i = 0; i < 8; ++i) s += part[i][tid];
        float cnt = (float)(en - st);
        gvec[tid] = s / fmaxf(cnt, 1.0f);
    }
    __syncthreads();
    if (tid < F2) {
        float a = fc1b[tid];
#pragma unroll
        for (int k = 0; k < F2; ++k) a += gvec[k] * sW1[k * F2 + tid];
        h1[tid] = fmaxf(a, 0.f);
    }
    __syncthreads();
    if (tid < F2) {
        float a = fc2b[tid];
#pragma unroll
        for (int k = 0; k < F2; ++k) a += h1[k] * sW2[k * F2 + tid];
        out[(size_t)g * F2 + tid] = a;
    }
}

extern "C" void kernel_launch(void* const* d_in, const int* in_sizes, int n_in,
                              void* d_out, int out_size, void* d_ws, size_t ws_size,
                              hipStream_t stream) {
    const float* x    = (const float*)d_in[0];
    const int*   ei   = (const int*)d_in[1];
    const int*   batch= (const int*)d_in[2];
    const float* W1   = (const float*)d_in[3];
    const float* b1   = (const float*)d_in[4];
    const float* W2   = (const float*)d_in[5];
    const float* b2   = (const float*)d_in[6];
    const float* fc1w = (const float*)d_in[7];
    const float* fc1b = (const float*)d_in[8];
    const float* fc2w = (const float*)d_in[9];
    const float* fc2b = (const float*)d_in[10];
    float* out = (float*)d_out;

    const int N = in_sizes[0] / FIN;       // 100000
    const int E = in_sizes[1] / 2;         // 1250000
    const int G = out_size / F2;           // 512
    const int* src = ei;
    const int* dst = ei + E;
    const int NB = (N + SCAN_B - 1) / SCAN_B;   // 391

    // ---- workspace layout (4-byte units) ----
    int* wsi = (int*)d_ws;
    int* indeg    = wsi;                 // N
    int* rowstart = indeg + N;           // N
    int* cursor   = rowstart + N;        // N
    int* bsum     = cursor + N;          // 512
    int* gstart   = bsum + 512;          // G+1
    int* csr      = gstart + (G + 1);    // E
    size_t ioff = (size_t)(3 * N + 512 + G + 1) + E;
    ioff = (ioff + 3) & ~(size_t)3;      // 16B align for float4
    float* dinv   = (float*)(wsi + ioff);            // N
    size_t nal = (size_t)((N + 3) & ~3);
    float* xn     = dinv + nal;                      // N*16
    float* y2     = xn + (size_t)N * 16;             // N*32
    float* h      = y2 + (size_t)N * F2;             // N*64
    float* out2   = h + (size_t)N * F1;              // N*32

    const int B = 256;
    hipMemsetAsync(indeg, 0, (size_t)N * sizeof(int), stream);

    hipLaunchKernelGGL(k_degree, dim3((E + B - 1) / B), dim3(B), 0, stream, dst, indeg, E);
    hipLaunchKernelGGL(k_scan1, dim3(NB), dim3(SCAN_B), 0, stream, indeg, bsum, N);
    hipLaunchKernelGGL(k_scan2, dim3(1), dim3(512), 0, stream, bsum, NB);
    hipLaunchKernelGGL(k_scan3, dim3(NB), dim3(SCAN_B), 0, stream,
                       indeg, bsum, rowstart, cursor, dinv, N);
    hipLaunchKernelGGL(k_fill_csr, dim3((E + B - 1) / B), dim3(B), 0, stream,
                       src, dst, cursor, csr, E);
    hipLaunchKernelGGL(k_xn, dim3(((long)N * 16 + B - 1) / B), dim3(B), 0, stream,
                       x, dinv, xn, N);
    hipLaunchKernelGGL(k_agg1t, dim3((N + 63) / 64), dim3(B), 0, stream,
                       (const float4*)xn, rowstart, indeg, dinv, csr, W1, b1, h, N);
    hipLaunchKernelGGL(k_trans2, dim3((N + 7) / 8), dim3(B), 0, stream,
                       h, W2, dinv, y2, N);
    hipLaunchKernelGGL(k_agg2, dim3((N + 31) / 32), dim3(B), 0, stream,
                       (const float4*)y2, rowstart, indeg, dinv, csr, b2,
                       (float4*)out2, N);
    hipLaunchKernelGGL(k_gstart, dim3((G + 1 + B - 1) / B), dim3(B), 0, stream,
                       batch, gstart, N, G);
    hipLaunchKernelGGL(k_poolmlp, dim3(G), dim3(B), 0, stream,
                       out2, gstart, fc1w, fc1b, fc2w, fc2b, out, G);
}